// Round 6
// baseline (947.066 us; speedup 1.0000x reference)
//
#include <hip/hip_runtime.h>

#define Bn 4096
#define Tn 100
#define Dn 64
#define Hn 128

typedef _Float16 half8v  __attribute__((ext_vector_type(8)));
typedef _Float16 half4v  __attribute__((ext_vector_type(4)));
typedef float    float4v __attribute__((ext_vector_type(4)));
typedef long     long2v  __attribute__((ext_vector_type(2)));

typedef __attribute__((address_space(1))) const unsigned int gu32;
typedef __attribute__((address_space(3))) unsigned int       lu32;

__device__ __forceinline__ float fast_tanh(float x) {
    float e = __expf(x + x);
    return 1.0f - 2.0f * __builtin_amdgcn_rcpf(e + 1.0f);
}
__device__ __forceinline__ float fast_sig(float x) {
    return __builtin_amdgcn_rcpf(1.0f + __expf(-x));
}
__device__ __forceinline__ float4v tanh4(float4v u) {
    float4v a;
#pragma unroll
    for (int r = 0; r < 4; r++) a[r] = fast_tanh(u[r]);
    return a;
}
__device__ __forceinline__ half4v pack4(float4v v) {
    half4v p;
#pragma unroll
    for (int r = 0; r < 4; r++) p[r] = (_Float16)v[r];
    return p;
}
__device__ __forceinline__ float4v cvt4(half4v h) {
    float4v f;
#pragma unroll
    for (int r = 0; r < 4; r++) f[r] = (float)h[r];
    return f;
}
__device__ __forceinline__ int pack_fp8x4(float a, float b, float c, float d) {
    int v = __builtin_amdgcn_cvt_pk_fp8_f32(a, b, 0, false);
    v = __builtin_amdgcn_cvt_pk_fp8_f32(c, d, v, true);
    return v;
}
__device__ __forceinline__ long pack_fp8x8s(float4v a, float4v b, float s) {
    int lo = pack_fp8x4(a[0]*s, a[1]*s, a[2]*s, a[3]*s);
    int hi = pack_fp8x4(b[0]*s, b[1]*s, b[2]*s, b[3]*s);
    return (long)(((unsigned long long)(unsigned)hi << 32) | (unsigned)lo);
}

// fp16 A-operand fragment of stationary weight W [n x ld]: lane gets W[n][k..k+7].
__device__ __forceinline__ half8v load_wfrag(const float* __restrict__ W, int ld, int n, int k) {
    const float* p = W + (size_t)n * ld + k;
    float4v a = *(const float4v*)p;
    float4v b = *(const float4v*)(p + 4);
    half8v r;
    r[0] = (_Float16)a[0]; r[1] = (_Float16)a[1]; r[2] = (_Float16)a[2]; r[3] = (_Float16)a[3];
    r[4] = (_Float16)b[0]; r[5] = (_Float16)b[1]; r[6] = (_Float16)b[2]; r[7] = (_Float16)b[3];
    return r;
}

// Persistent ODE-RNN. 256 blocks x 512 threads (8 waves, 2/SIMD, 1 block/CU).
// 19 barrier intervals/step: [u_h] + 15 fp8 RK exchanges + [Abar->h] + [gh+gi] + [GRU].
// R6 changes vs R5 (spill kill): Wih frags + all biases live in LDS (fp16); gi moved
// into the gh interval (no 12-reg liveness across RK); x staged by global_load_lds
// issued post-GRU so only the loop-top barrier drains it; waves_per_eu(2,2) grants
// a 256-VGPR budget (grid = 1 block/CU, occupancy unaffected).
__global__ __attribute__((amdgpu_flat_work_group_size(512, 512), amdgpu_waves_per_eu(2, 2)))
void odernn_kernel(
    const float* __restrict__ x_seq, const float* __restrict__ t_seq,
    const float* __restrict__ W1,   const float* __restrict__ b1,
    const float* __restrict__ W2,   const float* __restrict__ b2,
    const float* __restrict__ W_ih, const float* __restrict__ W_hh,
    const float* __restrict__ b_ih, const float* __restrict__ b_hh,
    const float* __restrict__ W_mu, const float* __restrict__ b_mu,
    const float* __restrict__ W_lv, const float* __restrict__ b_lv,
    float* __restrict__ out)
{
    __shared__ float    ts_l[Tn];                                              //   400 B
    __shared__ _Float16 vbuf[16 * 136];                                        //  4352 B
    __shared__ __attribute__((aligned(16))) unsigned char abuf8[2][16 * 144];  //  4608 B
    __shared__ __attribute__((aligned(16))) float xbuf[16 * 68];               //  4352 B (row stride 68 fl)
    __shared__ _Float16 wih_l[8 * 6 * 64 * 8];                                 // 49152 B
    __shared__ _Float16 bias_l[1024];                                          //  2048 B
    // total 64912 B <= 64 KB

    const int tid  = threadIdx.x;
    const int lane = tid & 63;
    const int w    = tid >> 6;
    const int q    = lane >> 4;
    const int m    = lane & 15;
    const int blk  = blockIdx.x;

    if (tid < Tn) ts_l[tid] = t_seq[tid];
    for (int i = tid; i < 16 * 136; i += 512) vbuf[i] = (_Float16)0.f;   // h0 = 0
    // biases -> fp16 LDS: [0:128)=b1 [128:256)=b2 [256:640)=b_ih [640:1024)=b_hh
    for (int i = tid; i < 1024; i += 512) {
        float v;
        if (i < 128) v = b1[i];
        else if (i < 256) v = b2[i - 128];
        else if (i < 640) v = b_ih[i - 256];
        else v = b_hh[i - 640];
        bias_l[i] = (_Float16)v;
    }
    // c1 = b2 @ W1^T staged temporarily in abuf8[0] (reused by RK later)
    float* c1s = (float*)abuf8[0];
    if (tid < Hn) {
        float acc = 0.f;
        const float* r1 = W1 + (size_t)tid * Hn;
#pragma unroll 4
        for (int j = 0; j < Hn; j++) acc += b2[j] * r1[j];
        c1s[tid] = acc;
    }
    // Wih fragments -> LDS fp16 (used once per step; not worth 24 persistent VGPRs)
#pragma unroll
    for (int f = 0; f < 6; f++) {
        int g = f >> 1, kt = f & 1;
        half8v fr = load_wfrag(W_ih, Dn, 128 * g + 16 * w + m, 32 * kt + q * 8);
        *(half8v*)(wih_l + ((w * 6 + f) * 64 + lane) * 8) = fr;
    }

    // ---- persistent register fragments ----
    const int n0 = 16 * w + m;
    half8v w1f[4], whhf[3][4];
#pragma unroll
    for (int kt = 0; kt < 4; kt++) w1f[kt] = load_wfrag(W1, Hn, n0, 32 * kt + q * 8);
#pragma unroll
    for (int g = 0; g < 3; g++)
#pragma unroll
        for (int kt = 0; kt < 4; kt++)
            whhf[g][kt] = load_wfrag(W_hh, Hn, 128 * g + n0, 32 * kt + q * 8);

    // ---- M = W1@W2 fp8 fragments (one-time VALU dot) + W2 fp8 fragments ----
    float4v aM[4][2];
#pragma unroll
    for (int kt = 0; kt < 4; kt++) {
        float4v zz = {0.f, 0.f, 0.f, 0.f};
        aM[kt][0] = zz; aM[kt][1] = zz;
    }
    {
        const float* w1row = W1 + (size_t)n0 * Hn;
        for (int j = 0; j < Hn; j++) {
            float w1v = w1row[j];
            const float* w2r = W2 + (size_t)j * Hn + q * 8;
#pragma unroll
            for (int kt = 0; kt < 4; kt++) {
                aM[kt][0] += w1v * *(const float4v*)(w2r + 32 * kt);
                aM[kt][1] += w1v * *(const float4v*)(w2r + 32 * kt + 4);
            }
        }
    }
    long w21f8[4], w2f8[4];
#pragma unroll
    for (int kt = 0; kt < 4; kt++) {
        w21f8[kt] = pack_fp8x8s(aM[kt][0], aM[kt][1], 64.0f);     // 64*M (avoid fp8 subnormals)
        const float* p = W2 + (size_t)n0 * Hn + 32 * kt + q * 8;
        w2f8[kt] = pack_fp8x8s(*(const float4v*)p, *(const float4v*)(p + 4), 64.0f);
    }

    float4v h = {0.f, 0.f, 0.f, 0.f};
    const float4v zero4 = {0.f, 0.f, 0.f, 0.f};

    const int wslot = m * 136 + 16 * w + q * 4;   // vbuf C-layout slot
    // fp8 writer position (permuted so reader's contiguous b128s give natural k-order)
    const int ppos = 64 * (w >> 2) + 16 * ((2 * (w & 3) + (q >> 1)) & 3)
                   + 8 * ((w >> 1) & 1) + 4 * (q & 1);

    auto store_a = [&](int pp, float4v v) {
        *(int*)(abuf8[pp] + m * 144 + ppos) = pack_fp8x4(v[0], v[1], v[2], v[3]);
    };
    auto gemm8 = [&](const long* Wf, int pp) -> float4v {
        const unsigned char* p = abuf8[pp] + m * 144;
        long2v L0 = *(const long2v*)(p + q * 16);
        long2v L1 = *(const long2v*)(p + 64 + q * 16);
        float4v o1 = zero4, o2 = zero4;
        o1 = __builtin_amdgcn_mfma_f32_16x16x32_fp8_fp8(Wf[0], L0[0], o1, 0, 0, 0);
        o2 = __builtin_amdgcn_mfma_f32_16x16x32_fp8_fp8(Wf[2], L1[0], o2, 0, 0, 0);
        o1 = __builtin_amdgcn_mfma_f32_16x16x32_fp8_fp8(Wf[1], L0[1], o1, 0, 0, 0);
        o2 = __builtin_amdgcn_mfma_f32_16x16x32_fp8_fp8(Wf[3], L1[1], o2, 0, 0, 0);
        return o1 + o2;
    };
    // async x stage: wave w DMAs rows 2w, 2w+1 (64 floats each) into xbuf
    const float* xbase = x_seq + (size_t)(blk * 16) * (Tn * Dn);
    auto load_x = [&](int t) {
#pragma unroll
        for (int i = 0; i < 2; i++) {
            int row = 2 * w + i;
            const float* gp = xbase + ((size_t)row * Tn + t) * Dn + lane;
            __builtin_amdgcn_global_load_lds((gu32*)gp, (lu32*)(xbuf + row * 68), 4, 0, 0);
        }
    };

    load_x(0);           // drained by the first loop-top barrier
    __syncthreads();     // publish init LDS (c1s, wih_l, bias_l, vbuf, ts_l)
    float4v c1q;
#pragma unroll
    for (int r = 0; r < 4; r++) c1q[r] = c1s[16 * w + q * 4 + r];
    // safe: first RK overwrite of abuf8[0] happens only after the loop-top barrier below

#pragma unroll 1
    for (int t = 0; t < Tn; ++t) {
        float tc   = ts_l[t];
        float tp   = (t > 0) ? ts_l[t - 1] : tc;
        float sub  = (tc - tp) * 0.25f;
        float hs   = 0.5f * sub;
        float hs64 = hs * (1.0f / 64.0f);
        float sb64 = sub * (1.0f / 64.0f);
        float s664 = sub * (1.0f / 384.0f);
        __syncthreads();                  // xbuf(t) DMA drained; vbuf(h) visible

        // ---- loop-top interval: u_h = h W1^T + b1 (fp16) ----
        float4v u_h;
        {
            const _Float16* vp = vbuf + m * 136 + q * 8;
            half8v bf0 = *(const half8v*)(vp);
            half8v bf1 = *(const half8v*)(vp + 32);
            half8v bf2 = *(const half8v*)(vp + 64);
            half8v bf3 = *(const half8v*)(vp + 96);
            float4v o1 = cvt4(*(const half4v*)(bias_l + 16 * w + q * 4));
            float4v o2 = zero4;
            o1 = __builtin_amdgcn_mfma_f32_16x16x32_f16(w1f[0], bf0, o1, 0, 0, 0);
            o2 = __builtin_amdgcn_mfma_f32_16x16x32_f16(w1f[2], bf2, o2, 0, 0, 0);
            o1 = __builtin_amdgcn_mfma_f32_16x16x32_f16(w1f[1], bf1, o1, 0, 0, 0);
            o2 = __builtin_amdgcn_mfma_f32_16x16x32_f16(w1f[3], bf3, o2, 0, 0, 0);
            u_h = o1 + o2;
        }

        if (sub != 0.0f) {
            float4v Abar = zero4;
#pragma unroll 1
            for (int s = 0; s < 4; s++) {
                float4v a1 = tanh4(u_h);
                float4v A = a1;
                store_a(0, a1);
                __syncthreads();
                float4v g = gemm8(w21f8, 0);
                float4v u = u_h + hs64 * g + hs * c1q;
                float4v a2 = tanh4(u);
                A += 2.0f * a2;
                store_a(1, a2);
                __syncthreads();
                g = gemm8(w21f8, 1);
                u = u_h + hs64 * g + hs * c1q;
                float4v a3 = tanh4(u);
                A += 2.0f * a3;
                store_a(0, a3);
                __syncthreads();
                g = gemm8(w21f8, 0);
                u = u_h + sb64 * g + sub * c1q;
                float4v a4 = tanh4(u);
                A += a4;
                Abar += A;
                if (s < 3) {                       // last substep: u_h dead, skip exchange
                    store_a(1, A);                 // |A| <= 6
                    __syncthreads();
                    g = gemm8(w21f8, 1);
                    u_h += s664 * g + sub * c1q;
                }
            }
            // ---- Abar exchange -> deferred h update ----
            store_a(1, Abar);                      // |Abar| <= 24
            __syncthreads();
            float4v gw = gemm8(w2f8, 1);
            h += s664 * gw + (4.0f * sub) * cvt4(*(const half4v*)(bias_l + 128 + 16 * w + q * 4));
            *(half4v*)(vbuf + wslot) = pack4(h);   // publish post-RK h
            __syncthreads();
        }

        // ---- gh + gi interval (gi moved here: no liveness across RK) ----
        float4v gh[3], gi[3];
        {
            const _Float16* vp = vbuf + m * 136 + q * 8;
            half8v bf0 = *(const half8v*)(vp);
            half8v bf1 = *(const half8v*)(vp + 32);
            half8v bf2 = *(const half8v*)(vp + 64);
            half8v bf3 = *(const half8v*)(vp + 96);
            // x fragments built in-register from fp32 xbuf
            const float* xr = xbuf + m * 68;
            half8v xf[2];
#pragma unroll
            for (int kt = 0; kt < 2; kt++) {
                float4v xa = *(const float4v*)(xr + 32 * kt + q * 8);
                float4v xb = *(const float4v*)(xr + 32 * kt + q * 8 + 4);
#pragma unroll
                for (int r = 0; r < 4; r++) {
                    xf[kt][r]     = (_Float16)xa[r];
                    xf[kt][r + 4] = (_Float16)xb[r];
                }
            }
#pragma unroll
            for (int g = 0; g < 3; g++) {
                float4v acc = cvt4(*(const half4v*)(bias_l + 640 + 128 * g + 16 * w + q * 4));
                acc = __builtin_amdgcn_mfma_f32_16x16x32_f16(whhf[g][0], bf0, acc, 0, 0, 0);
                acc = __builtin_amdgcn_mfma_f32_16x16x32_f16(whhf[g][1], bf1, acc, 0, 0, 0);
                acc = __builtin_amdgcn_mfma_f32_16x16x32_f16(whhf[g][2], bf2, acc, 0, 0, 0);
                acc = __builtin_amdgcn_mfma_f32_16x16x32_f16(whhf[g][3], bf3, acc, 0, 0, 0);
                gh[g] = acc;
                float4v acg = cvt4(*(const half4v*)(bias_l + 256 + 128 * g + 16 * w + q * 4));
#pragma unroll
                for (int kt = 0; kt < 2; kt++) {
                    half8v wf = *(const half8v*)(wih_l + ((w * 6 + g * 2 + kt) * 64 + lane) * 8);
                    acg = __builtin_amdgcn_mfma_f32_16x16x32_f16(wf, xf[kt], acg, 0, 0, 0);
                }
                gi[g] = acg;
            }
        }
        __syncthreads();   // all waves done reading vbuf/xbuf before overwrite

        // ---- GRU (registers) + publish h ----
        {
            half4v pk;
#pragma unroll
            for (int r = 0; r < 4; r++) {
                float rr = fast_sig(gi[0][r] + gh[0][r]);
                float zz = fast_sig(gi[1][r] + gh[1][r]);
                float nn = fast_tanh(gi[2][r] + rr * gh[2][r]);
                float hv = (1.0f - zz) * nn + zz * h[r];
                h[r] = hv;
                pk[r] = (_Float16)hv;
            }
            *(half4v*)(vbuf + wslot) = pk;
        }
        if (t + 1 < Tn) load_x(t + 1);   // drained only at next loop-top barrier
        // loop-top barrier publishes vbuf
    }

    __syncthreads();

    // ---- epilogue: mu / logvar (fresh fp16 weight fragments) ----
#pragma unroll
    for (int mat = 0; mat < 2; mat++) {
        const float* Wm = mat ? W_lv : W_mu;
        const float* bm = mat ? b_lv : b_mu;
        float4v acc = *(const float4v*)(bm + 16 * w + q * 4);
        const _Float16* p = vbuf + m * 136 + q * 8;
#pragma unroll
        for (int kt = 0; kt < 4; kt++) {
            half8v af = load_wfrag(Wm, Hn, n0, 32 * kt + q * 8);
            acc = __builtin_amdgcn_mfma_f32_16x16x32_f16(af, *(const half8v*)(p + kt * 32), acc, 0, 0, 0);
        }
        *(float4v*)(out + (size_t)mat * Bn * Hn + (size_t)(blk * 16 + m) * Hn + 16 * w + q * 4) = acc;
    }
}

extern "C" void kernel_launch(void* const* d_in, const int* in_sizes, int n_in,
                              void* d_out, int out_size, void* d_ws, size_t ws_size,
                              hipStream_t stream) {
    (void)in_sizes; (void)n_in; (void)d_ws; (void)ws_size; (void)out_size;
    odernn_kernel<<<dim3(Bn / 16), dim3(512), 0, stream>>>(
        (const float*)d_in[0],  (const float*)d_in[1],  (const float*)d_in[2],
        (const float*)d_in[3],  (const float*)d_in[4],  (const float*)d_in[5],
        (const float*)d_in[6],  (const float*)d_in[7],  (const float*)d_in[8],
        (const float*)d_in[9],  (const float*)d_in[10], (const float*)d_in[11],
        (const float*)d_in[12], (const float*)d_in[13], (float*)d_out);
}

// Round 7
// 818.986 us; speedup vs baseline: 1.1564x; 1.1564x over previous
//
#include <hip/hip_runtime.h>

#define Bn 4096
#define Tn 100
#define Dn 64
#define Hn 128

typedef _Float16 half8v  __attribute__((ext_vector_type(8)));
typedef _Float16 half4v  __attribute__((ext_vector_type(4)));
typedef float    float4v __attribute__((ext_vector_type(4)));
typedef float    float2v __attribute__((ext_vector_type(2)));

__device__ __forceinline__ float fast_tanh(float x) {
    float e = __expf(x + x);
    return 1.0f - 2.0f * __builtin_amdgcn_rcpf(e + 1.0f);
}
__device__ __forceinline__ float fast_sig(float x) {
    return __builtin_amdgcn_rcpf(1.0f + __expf(-x));
}
__device__ __forceinline__ float4v tanh4(float4v u) {
    float4v a;
#pragma unroll
    for (int r = 0; r < 4; r++) a[r] = fast_tanh(u[r]);
    return a;
}
__device__ __forceinline__ half4v pack4(float4v v) {
    half4v p;
#pragma unroll
    for (int r = 0; r < 4; r++) p[r] = (_Float16)v[r];
    return p;
}

// fp16 A-operand fragment of stationary weight W [n x ld]: lane gets W[n][k..k+7].
__device__ __forceinline__ half8v load_wfrag(const float* __restrict__ W, int ld, int n, int k) {
    const float* p = W + (size_t)n * ld + k;
    float4v a = *(const float4v*)p;
    float4v b = *(const float4v*)(p + 4);
    half8v r;
    r[0] = (_Float16)a[0]; r[1] = (_Float16)a[1]; r[2] = (_Float16)a[2]; r[3] = (_Float16)a[3];
    r[4] = (_Float16)b[0]; r[5] = (_Float16)b[1]; r[6] = (_Float16)b[2]; r[7] = (_Float16)b[3];
    return r;
}

// Persistent ODE-RNN. 256 blocks x 512 threads (8 waves, 2/SIMD, 1 block/CU).
// R7 = R3 structure (fp16 exchange -- best measured) + merged tail (19 intervals)
// + amdgpu_waves_per_eu(2,2): grid is exactly 1 block/CU, so the default 128-VGPR
// cap (sized for a phantom 2nd block) only causes scratch spill (R3: WRITE 27MB).
// Granting 256 VGPRs keeps all hot state resident. Only cold Wih frags go to LDS.
__global__ __attribute__((amdgpu_flat_work_group_size(512, 512), amdgpu_waves_per_eu(2, 2)))
void odernn_kernel(
    const float* __restrict__ x_seq, const float* __restrict__ t_seq,
    const float* __restrict__ W1,   const float* __restrict__ b1,
    const float* __restrict__ W2,   const float* __restrict__ b2,
    const float* __restrict__ W_ih, const float* __restrict__ W_hh,
    const float* __restrict__ b_ih, const float* __restrict__ b_hh,
    const float* __restrict__ W_mu, const float* __restrict__ b_mu,
    const float* __restrict__ W_lv, const float* __restrict__ b_lv,
    float* __restrict__ out)
{
    __shared__ float    ts_l[Tn];
    __shared__ _Float16 vbuf[16 * 136];      // h exchange (fp16, B-layout)
    __shared__ _Float16 abuf[2][16 * 136];   // a_i / A / Abar exchange, ping-pong
    __shared__ _Float16 xbuf[16 * 72];       // x_t staging
    __shared__ _Float16 wih_l[8 * 6 * 64 * 8];  // Wih frags (cold: 1 use/step)
    __shared__ float    c1s[Hn];             // b2 @ W1^T

    const int tid  = threadIdx.x;
    const int lane = tid & 63;
    const int w    = tid >> 6;        // wave 0..7 = n-tile owner
    const int q    = lane >> 4;
    const int m    = lane & 15;
    const int blk  = blockIdx.x;

    if (tid < Tn) ts_l[tid] = t_seq[tid];
    for (int i = tid; i < 16 * 136; i += 512) vbuf[i] = (_Float16)0.f;   // h0 = 0
    if (tid < Hn) {
        float acc = 0.f;
        const float* r1 = W1 + (size_t)tid * Hn;
#pragma unroll 4
        for (int j = 0; j < Hn; j++) acc += b2[j] * r1[j];
        c1s[tid] = acc;
    }
    // Wih fragments -> LDS (per-wave layout [w][g*2+kt][lane][8])
#pragma unroll
    for (int f = 0; f < 6; f++) {
        int g = f >> 1, kt = f & 1;
        half8v fr = load_wfrag(W_ih, Dn, 128 * g + 16 * w + m, 32 * kt + q * 8);
        *(half8v*)(wih_l + ((w * 6 + f) * 64 + lane) * 8) = fr;
    }

    // ---- persistent register fragments (fits: waves_per_eu(2,2) => 256-VGPR budget) ----
    const int n0 = 16 * w + m;
    half8v w1f[4], w2f[4], whhf[3][4];
#pragma unroll
    for (int kt = 0; kt < 4; kt++) {
        w1f[kt] = load_wfrag(W1, Hn, n0, 32 * kt + q * 8);
        w2f[kt] = load_wfrag(W2, Hn, n0, 32 * kt + q * 8);
    }
#pragma unroll
    for (int g = 0; g < 3; g++)
#pragma unroll
        for (int kt = 0; kt < 4; kt++)
            whhf[g][kt] = load_wfrag(W_hh, Hn, 128 * g + n0, 32 * kt + q * 8);

    float4v b1q = *(const float4v*)(b1 + 16 * w + q * 4);
    float4v b2q = *(const float4v*)(b2 + 16 * w + q * 4);
    float4v bihq[3], bhhq[3];
#pragma unroll
    for (int g = 0; g < 3; g++) {
        bihq[g] = *(const float4v*)(b_ih + 128 * g + 16 * w + q * 4);
        bhhq[g] = *(const float4v*)(b_hh + 128 * g + 16 * w + q * 4);
    }

    // ---- M = W1@W2 fp16 fragments (one-time VALU dot) ----
    float4v aM[4][2];
#pragma unroll
    for (int kt = 0; kt < 4; kt++) {
        float4v zz = {0.f, 0.f, 0.f, 0.f};
        aM[kt][0] = zz; aM[kt][1] = zz;
    }
    {
        const float* w1row = W1 + (size_t)n0 * Hn;
        for (int j = 0; j < Hn; j++) {
            float w1v = w1row[j];
            const float* w2r = W2 + (size_t)j * Hn + q * 8;
#pragma unroll
            for (int kt = 0; kt < 4; kt++) {
                aM[kt][0] += w1v * *(const float4v*)(w2r + 32 * kt);
                aM[kt][1] += w1v * *(const float4v*)(w2r + 32 * kt + 4);
            }
        }
    }
    half8v w21f[4];
#pragma unroll
    for (int kt = 0; kt < 4; kt++) {
#pragma unroll
        for (int r = 0; r < 4; r++) {
            w21f[kt][r]     = (_Float16)aM[kt][0][r];
            w21f[kt][r + 4] = (_Float16)aM[kt][1][r];
        }
    }

    float4v h = {0.f, 0.f, 0.f, 0.f};
    const float4v zero4 = {0.f, 0.f, 0.f, 0.f};

    const int xrow = tid >> 5;
    const int xcol = (tid & 31) * 2;
    const float* xptr = x_seq + (size_t)(blk * 16 + xrow) * (Tn * Dn) + xcol;
    float2v xreg = *(const float2v*)xptr;

    const int wslot = m * 136 + 16 * w + q * 4;   // C-layout store slot

    // K=128 fp16 GEMM: 4x ds_read_b128, 4 MFMAs in 2 chains
    auto gemm4 = [&](const half8v* Wf, const _Float16* base, float4v cin) -> float4v {
        const _Float16* p = base + m * 136 + q * 8;
        half8v bf0 = *(const half8v*)(p);
        half8v bf1 = *(const half8v*)(p + 32);
        half8v bf2 = *(const half8v*)(p + 64);
        half8v bf3 = *(const half8v*)(p + 96);
        float4v o1 = cin;
        float4v o2 = zero4;
        o1 = __builtin_amdgcn_mfma_f32_16x16x32_f16(Wf[0], bf0, o1, 0, 0, 0);
        o2 = __builtin_amdgcn_mfma_f32_16x16x32_f16(Wf[2], bf2, o2, 0, 0, 0);
        o1 = __builtin_amdgcn_mfma_f32_16x16x32_f16(Wf[1], bf1, o1, 0, 0, 0);
        o2 = __builtin_amdgcn_mfma_f32_16x16x32_f16(Wf[3], bf3, o2, 0, 0, 0);
        return o1 + o2;
    };

    float4v c1q;
    __syncthreads();     // publish ts_l, c1s, wih_l, vbuf(h0)
#pragma unroll
    for (int r = 0; r < 4; r++) c1q[r] = c1s[16 * w + q * 4 + r];

#pragma unroll 1
    for (int t = 0; t < Tn; ++t) {
        {
            _Float16* xp = xbuf + xrow * 72 + xcol;
            xp[0] = (_Float16)xreg[0]; xp[1] = (_Float16)xreg[1];
        }
        float tc  = ts_l[t];
        float tp  = (t > 0) ? ts_l[t - 1] : tc;
        float sub = (tc - tp) * 0.25f;
        float hs  = 0.5f * sub;
        float s6  = sub * (1.0f / 6.0f);
        __syncthreads();                  // publish xbuf + vbuf(h)
        if (t + 1 < Tn) xreg = *(const float2v*)(xptr + (t + 1) * Dn);  // ~2 intervals of slack before a barrier drains it

        // ---- loop-top interval: gi = x Wih^T + bih  and  u_h = h W1^T + b1 ----
        float4v gi[3];
        {
            const _Float16* xp = xbuf + m * 72 + q * 8;
            half8v xf0 = *(const half8v*)(xp);
            half8v xf1 = *(const half8v*)(xp + 32);
#pragma unroll
            for (int g = 0; g < 3; g++) {
                float4v acc = bihq[g];
                half8v wf0 = *(const half8v*)(wih_l + ((w * 6 + g * 2 + 0) * 64 + lane) * 8);
                half8v wf1 = *(const half8v*)(wih_l + ((w * 6 + g * 2 + 1) * 64 + lane) * 8);
                acc = __builtin_amdgcn_mfma_f32_16x16x32_f16(wf0, xf0, acc, 0, 0, 0);
                acc = __builtin_amdgcn_mfma_f32_16x16x32_f16(wf1, xf1, acc, 0, 0, 0);
                gi[g] = acc;
            }
        }
        float4v u_h = gemm4(w1f, vbuf, b1q);

        if (sub != 0.0f) {
            float4v Abar = zero4;
#pragma unroll 1
            for (int s = 0; s < 4; s++) {
                float4v a1 = tanh4(u_h);
                float4v A = a1;
                *(half4v*)(abuf[0] + wslot) = pack4(a1);
                __syncthreads();
                float4v g = gemm4(w21f, abuf[0], zero4);
                float4v u = u_h + hs * g + hs * c1q;
                float4v a2 = tanh4(u);
                A += 2.0f * a2;
                *(half4v*)(abuf[1] + wslot) = pack4(a2);
                __syncthreads();
                g = gemm4(w21f, abuf[1], zero4);
                u = u_h + hs * g + hs * c1q;
                float4v a3 = tanh4(u);
                A += 2.0f * a3;
                *(half4v*)(abuf[0] + wslot) = pack4(a3);
                __syncthreads();
                g = gemm4(w21f, abuf[0], zero4);
                u = u_h + sub * g + sub * c1q;
                float4v a4 = tanh4(u);
                A += a4;
                Abar += A;
                if (s < 3) {                       // last substep: u_h dead, skip exchange
                    *(half4v*)(abuf[1] + wslot) = pack4(A);   // |A| <= 6
                    __syncthreads();
                    g = gemm4(w21f, abuf[1], zero4);
                    u_h += s6 * g + sub * c1q;
                }
            }
            // ---- Abar exchange -> deferred h update (one W2-GEMM per step) ----
            *(half4v*)(abuf[1] + wslot) = pack4(Abar);        // |Abar| <= 24
            __syncthreads();
            float4v gw = gemm4(w2f, abuf[1], zero4);
            h += s6 * gw + (4.0f * sub) * b2q;
            *(half4v*)(vbuf + wslot) = pack4(h);   // publish post-RK h
            __syncthreads();
        }

        // ---- gh = h Whh^T + bhh ----
        float4v gh[3];
        {
            const _Float16* vp = vbuf + m * 136 + q * 8;
            half8v bf0 = *(const half8v*)(vp);
            half8v bf1 = *(const half8v*)(vp + 32);
            half8v bf2 = *(const half8v*)(vp + 64);
            half8v bf3 = *(const half8v*)(vp + 96);
#pragma unroll
            for (int g = 0; g < 3; g++) {
                float4v acc = bhhq[g];
                acc = __builtin_amdgcn_mfma_f32_16x16x32_f16(whhf[g][0], bf0, acc, 0, 0, 0);
                acc = __builtin_amdgcn_mfma_f32_16x16x32_f16(whhf[g][1], bf1, acc, 0, 0, 0);
                acc = __builtin_amdgcn_mfma_f32_16x16x32_f16(whhf[g][2], bf2, acc, 0, 0, 0);
                acc = __builtin_amdgcn_mfma_f32_16x16x32_f16(whhf[g][3], bf3, acc, 0, 0, 0);
                gh[g] = acc;
            }
        }
        __syncthreads();   // all waves done reading vbuf before GRU overwrite

        // ---- GRU (registers) + publish h ----
        {
            half4v pk;
#pragma unroll
            for (int r = 0; r < 4; r++) {
                float rr = fast_sig(gi[0][r] + gh[0][r]);
                float zz = fast_sig(gi[1][r] + gh[1][r]);
                float nn = fast_tanh(gi[2][r] + rr * gh[2][r]);
                float hv = (1.0f - zz) * nn + zz * h[r];
                h[r] = hv;
                pk[r] = (_Float16)hv;
            }
            *(half4v*)(vbuf + wslot) = pk;
        }
        // loop-top barrier publishes vbuf
    }

    __syncthreads();

    // ---- epilogue: mu / logvar (fresh fp16 weight fragments) ----
#pragma unroll
    for (int mat = 0; mat < 2; mat++) {
        const float* Wm = mat ? W_lv : W_mu;
        const float* bm = mat ? b_lv : b_mu;
        float4v acc = *(const float4v*)(bm + 16 * w + q * 4);
        const _Float16* p = vbuf + m * 136 + q * 8;
#pragma unroll
        for (int kt = 0; kt < 4; kt++) {
            half8v af = load_wfrag(Wm, Hn, n0, 32 * kt + q * 8);
            acc = __builtin_amdgcn_mfma_f32_16x16x32_f16(af, *(const half8v*)(p + kt * 32), acc, 0, 0, 0);
        }
        *(float4v*)(out + (size_t)mat * Bn * Hn + (size_t)(blk * 16 + m) * Hn + 16 * w + q * 4) = acc;
    }
}

extern "C" void kernel_launch(void* const* d_in, const int* in_sizes, int n_in,
                              void* d_out, int out_size, void* d_ws, size_t ws_size,
                              hipStream_t stream) {
    (void)in_sizes; (void)n_in; (void)d_ws; (void)ws_size; (void)out_size;
    odernn_kernel<<<dim3(Bn / 16), dim3(512), 0, stream>>>(
        (const float*)d_in[0],  (const float*)d_in[1],  (const float*)d_in[2],
        (const float*)d_in[3],  (const float*)d_in[4],  (const float*)d_in[5],
        (const float*)d_in[6],  (const float*)d_in[7],  (const float*)d_in[8],
        (const float*)d_in[9],  (const float*)d_in[10], (const float*)d_in[11],
        (const float*)d_in[12], (const float*)d_in[13], (float*)d_out);
}